// Round 4
// baseline (260.937 us; speedup 1.0000x reference)
//
#include <hip/hip_runtime.h>
#include <cmath>

namespace {
constexpr int H = 256, W = 256, HWp = H * W;
// fast-path workspace: w1tb (73728 B) + psi (1 MB) + Xt_r + Xt_i (33.55 MB each)
constexpr size_t PLANE = (size_t)4 * HWp * 64 * 2;  // one NHWC fp16 tensor
constexpr size_t NEED_FAST = 73728 + (1u << 20) + 2 * PLANE;
}

typedef _Float16 f16;
typedef __attribute__((ext_vector_type(8))) _Float16 f16x8;
typedef __attribute__((ext_vector_type(4))) float f32x4;
typedef __attribute__((ext_vector_type(4))) unsigned int u32x4;

// K_wt: w1 [co][ci][3][3] fp32 -> w1tb [k9][co][ci] fp16
__global__ void k_wt(const float* __restrict__ w1, f16* __restrict__ w1tb) {
    int i = blockIdx.x * 256 + threadIdx.x;
    if (i >= 64 * 576) return;
    int co = i / 576, r = i - co * 576;
    int ci = r / 9, k9 = r - ci * 9;
    w1tb[(k9 * 64 + co) * 64 + ci] = (f16)w1[i];
}

// K_xt: one 64-ch plane-set NCHW fp32 -> NHWC fp16. float4 reads via LDS.
__global__ __launch_bounds__(256) void k_xt(const float* __restrict__ x,
                                            f16* __restrict__ dst) {
    __shared__ f16 tile[64][80];  // row 160 B, 16B-aligned
    const int t = threadIdx.x;
    const int p0 = blockIdx.x * 64;
    const size_t base = (size_t)blockIdx.y * 64 * HWp;
#pragma unroll
    for (int r = 0; r < 4; ++r) {
        int q = r * 256 + t;            // 0..1023 float4s of the 64px x 64ci tile
        int ci = q >> 4, px4 = (q & 15) * 4;
        f32x4 v = *reinterpret_cast<const f32x4*>(x + base + (size_t)ci * HWp + p0 + px4);
#pragma unroll
        for (int j = 0; j < 4; ++j) tile[px4 + j][ci] = (f16)v[j];
    }
    __syncthreads();
    const int px = t >> 2, q = t & 3;
    u32x4* d = reinterpret_cast<u32x4*>(dst + ((size_t)blockIdx.y * HWp + p0 + px) * 64 + q * 16);
    const u32x4* s = reinterpret_cast<const u32x4*>(&tile[px][q * 16]);
    d[0] = s[0];
    d[1] = s[1];
}

// K1: conv1 via f16 MFMA. Block = one row (256 px), 4 waves x (64 px, 64 co).
__global__ __launch_bounds__(256, 4) void k_conv1(
        const f16* __restrict__ Xt,    // [B][HWp][64] fp16
        const f16* __restrict__ w1tb,  // [9][64co][64ci] fp16
        const float* __restrict__ b1,
        f16* __restrict__ act) {       // [B][HWp][64] fp16
    const int wid = threadIdx.x >> 6;
    const int lane = threadIdx.x & 63;
    const int y = blockIdx.x;
    const int b = blockIdx.y;
    const int lr = lane & 15;
    const int lg = lane >> 4;

    const int x_base = wid * 64;
    f32x4 acc[4][4];
#pragma unroll
    for (int m = 0; m < 4; ++m)
#pragma unroll
        for (int n = 0; n < 4; ++n) acc[m][n] = (f32x4)0.f;

    const size_t row_base = ((size_t)b * H + y) * W;
    const f16* Arow = Xt + (row_base + x_base + lr) * 64 + lg * 8;
    const f16* Bb = w1tb + (lr * 64 + lg * 8);
    const f16x8 zf = (f16x8)(f16)0.f;

    for (int dy = -1; dy <= 1; ++dy) {
        const int yy = y + dy;
        if ((unsigned)yy >= (unsigned)H) continue;
        const f16* Ar = Arow + (ptrdiff_t)dy * W * 64;
#pragma unroll
        for (int dx = -1; dx <= 1; ++dx) {
            const int k9 = (dy + 1) * 3 + (dx + 1);
            const f16* Bk = Bb + k9 * 64 * 64;
#pragma unroll
            for (int ci0 = 0; ci0 < 64; ci0 += 32) {
                f16x8 bf[4];
#pragma unroll
                for (int n = 0; n < 4; ++n)
                    bf[n] = *reinterpret_cast<const f16x8*>(Bk + n * 16 * 64 + ci0);
#pragma unroll
                for (int m = 0; m < 4; ++m) {
                    const int gx = x_base + m * 16 + lr + dx;
                    f16x8 af = ((unsigned)gx < (unsigned)W)
                        ? *reinterpret_cast<const f16x8*>(Ar + (ptrdiff_t)(m * 16 + dx) * 64 + ci0)
                        : zf;
#pragma unroll
                    for (int n = 0; n < 4; ++n)
                        acc[m][n] = __builtin_amdgcn_mfma_f32_16x16x32_f16(
                            af, bf[n], acc[m][n], 0, 0, 0);
                }
            }
        }
    }

#pragma unroll
    for (int m = 0; m < 4; ++m) {
        const int px = x_base + m * 16 + lg * 4;
        f16* ap = act + (row_base + px) * 64;
#pragma unroll
        for (int n = 0; n < 4; ++n) {
            const int co = n * 16 + lr;
            const float bias = b1[co];
#pragma unroll
            for (int r = 0; r < 4; ++r) {
                float v = acc[m][n][r] + bias;
                v = v / (1.f + __expf(-v));
                ap[(size_t)r * 64 + co] = (f16)v;
            }
        }
    }
}

// K2: conv2 (64->1) + *dt -> psi. NHWC fp16 input, f16x8 vector loads.
__global__ __launch_bounds__(256) void k_conv2(
        const f16* __restrict__ act, const float* __restrict__ w2,
        const float* __restrict__ b2, const float* __restrict__ dtp,
        float* __restrict__ psi) {
    const int tx = threadIdx.x & 31, ty = threadIdx.x >> 5;
    const int px = blockIdx.x * 32 + tx;
    const int py = blockIdx.y * 8 + ty;
    const int b = blockIdx.z;

    float a0 = 0.f, a1 = 0.f, a2 = 0.f, a3 = 0.f;
#pragma unroll
    for (int dy = -1; dy <= 1; ++dy) {
        const int yy = py + dy;
        if ((unsigned)yy >= (unsigned)H) continue;
#pragma unroll
        for (int dx = -1; dx <= 1; ++dx) {
            const int xx = px + dx;
            const int k9 = (dy + 1) * 3 + (dx + 1);
            if ((unsigned)xx < (unsigned)W) {
                const f16x8* ap = reinterpret_cast<const f16x8*>(
                    act + (((size_t)b * H + yy) * W + xx) * 64);
                const float* wp = w2 + k9;
#pragma unroll
                for (int g = 0; g < 8; ++g) {
                    const f16x8 v = ap[g];
                    const int cb = g * 8;
                    a0 = fmaf((float)v[0], wp[(cb + 0) * 9], a0);
                    a1 = fmaf((float)v[1], wp[(cb + 1) * 9], a1);
                    a2 = fmaf((float)v[2], wp[(cb + 2) * 9], a2);
                    a3 = fmaf((float)v[3], wp[(cb + 3) * 9], a3);
                    a0 = fmaf((float)v[4], wp[(cb + 4) * 9], a0);
                    a1 = fmaf((float)v[5], wp[(cb + 5) * 9], a1);
                    a2 = fmaf((float)v[6], wp[(cb + 6) * 9], a2);
                    a3 = fmaf((float)v[7], wp[(cb + 7) * 9], a3);
                }
            }
        }
    }
    psi[((size_t)b * H + py) * W + px] = ((a0 + a1) + (a2 + a3) + b2[0]) * dtp[0];
}

// K3 fast: curl + bilinear sample from NHWC fp16. Thread = 4 px x 16 ch.
// Corner loads = 2x uint4 (32 B); stores = float4.
__global__ __launch_bounds__(256) void k_sample_fast(
        const f16* __restrict__ Xt_r, const f16* __restrict__ Xt_i,
        const float* __restrict__ psi, float* __restrict__ out) {
    const int lane = threadIdx.x & 63;
    const int y = blockIdx.x * 4 + (threadIdx.x >> 6);
    const int b = blockIdx.y >> 3;
    const int cg = blockIdx.y & 7;   // combined channel group: base = cg*16
    const int px0 = lane * 4;

    const f16* src = ((cg < 4) ? Xt_r : Xt_i) + (size_t)b * HWp * 64 + (cg & 3) * 16;
    const float* pb = psi + b * HWp;

    f32x4 outv[16];
#pragma unroll
    for (int i = 0; i < 4; ++i) {
        const int px = px0 + i;
        const int yp = min(y + 1, H - 1), ym = max(y - 1, 0);
        const int xp = min(px + 1, W - 1), xm = max(px - 1, 0);
        const float u = 0.5f * (pb[yp * W + px] - pb[ym * W + px]);
        const float v = -0.5f * (pb[y * W + xp] - pb[y * W + xm]);

        const float gx = (-1.f + 2.f * px / (float)(W - 1)) - u * (2.f / (float)W);
        const float gy = (-1.f + 2.f * y / (float)(H - 1)) - v * (2.f / (float)H);

        float ix = fminf(fmaxf((gx + 1.f) * 0.5f * (float)(W - 1), 0.f), (float)(W - 1));
        float iy = fminf(fmaxf((gy + 1.f) * 0.5f * (float)(H - 1), 0.f), (float)(H - 1));
        const float xf = floorf(ix), yf = floorf(iy);
        const float wx = ix - xf, wy = iy - yf;
        const int ix0 = (int)xf, iy0 = (int)yf;
        const int ix1 = min(ix0 + 1, W - 1), iy1 = min(iy0 + 1, H - 1);

        const float w00 = (1.f - wx) * (1.f - wy), w01 = wx * (1.f - wy);
        const float w10 = (1.f - wx) * wy, w11 = wx * wy;

        const f16x8* p00 = reinterpret_cast<const f16x8*>(src + (size_t)(iy0 * W + ix0) * 64);
        const f16x8* p01 = reinterpret_cast<const f16x8*>(src + (size_t)(iy0 * W + ix1) * 64);
        const f16x8* p10 = reinterpret_cast<const f16x8*>(src + (size_t)(iy1 * W + ix0) * 64);
        const f16x8* p11 = reinterpret_cast<const f16x8*>(src + (size_t)(iy1 * W + ix1) * 64);
        const f16x8 h00a = p00[0], h00b = p00[1];
        const f16x8 h01a = p01[0], h01b = p01[1];
        const f16x8 h10a = p10[0], h10b = p10[1];
        const f16x8 h11a = p11[0], h11b = p11[1];
#pragma unroll
        for (int c = 0; c < 8; ++c)
            outv[c][i] = (float)h00a[c] * w00 + (float)h01a[c] * w01 +
                         (float)h10a[c] * w10 + (float)h11a[c] * w11;
#pragma unroll
        for (int c = 0; c < 8; ++c)
            outv[8 + c][i] = (float)h00b[c] * w00 + (float)h01b[c] * w01 +
                             (float)h10b[c] * w10 + (float)h11b[c] * w11;
    }

    float* ob = out + ((size_t)b * 128 + cg * 16) * HWp + y * W + px0;
#pragma unroll
    for (int c = 0; c < 16; ++c)
        *reinterpret_cast<f32x4*>(ob + (size_t)c * HWp) = outv[c];
}

// K3 fallback (proven round-3 version): scalar gather from fp32 NCHW.
__global__ __launch_bounds__(256) void k_sample_fb(
        const float* __restrict__ zr, const float* __restrict__ zi,
        const float* __restrict__ psi, float* __restrict__ out) {
    const int tx = threadIdx.x & 31, ty = threadIdx.x >> 5;
    const int px = blockIdx.x * 32 + tx;
    const int py = blockIdx.y * 8 + ty;
    const int b  = blockIdx.z >> 3;
    const int c0 = (blockIdx.z & 7) * 16;

    const float* pb = psi + b * HWp;
    const int yp = min(py + 1, H - 1), ym = max(py - 1, 0);
    const int xp = min(px + 1, W - 1), xm = max(px - 1, 0);
    const float u = 0.5f * (pb[yp * W + px] - pb[ym * W + px]);
    const float v = -0.5f * (pb[py * W + xp] - pb[py * W + xm]);

    const float gx = (-1.f + 2.f * px / (float)(W - 1)) - u * (2.f / (float)W);
    const float gy = (-1.f + 2.f * py / (float)(H - 1)) - v * (2.f / (float)H);

    float ix = fminf(fmaxf((gx + 1.f) * 0.5f * (float)(W - 1), 0.f), (float)(W - 1));
    float iy = fminf(fmaxf((gy + 1.f) * 0.5f * (float)(H - 1), 0.f), (float)(H - 1));
    const float xf = floorf(ix), yf = floorf(iy);
    const float wx = ix - xf, wy = iy - yf;
    const int ix0 = (int)xf, iy0 = (int)yf;
    const int ix1 = min(ix0 + 1, W - 1), iy1 = min(iy0 + 1, H - 1);

    const int o00 = iy0 * W + ix0, o01 = iy0 * W + ix1;
    const int o10 = iy1 * W + ix0, o11 = iy1 * W + ix1;
    const float w00 = (1.f - wx) * (1.f - wy), w01 = wx * (1.f - wy);
    const float w10 = (1.f - wx) * wy, w11 = wx * wy;

    const float* src0 = (c0 < 64) ? (zr + (size_t)b * 64 * HWp + (size_t)c0 * HWp)
                                  : (zi + (size_t)b * 64 * HWp + (size_t)(c0 - 64) * HWp);
    float* ob = out + ((size_t)b * 128 + c0) * HWp + py * W + px;
#pragma unroll
    for (int c = 0; c < 16; ++c) {
        const float* p = src0 + (size_t)c * HWp;
        ob[(size_t)c * HWp] = p[o00] * w00 + p[o01] * w01 + p[o10] * w10 + p[o11] * w11;
    }
}

extern "C" void kernel_launch(void* const* d_in, const int* in_sizes, int n_in,
                              void* d_out, int out_size, void* d_ws, size_t ws_size,
                              hipStream_t stream) {
    const float* z_real = (const float*)d_in[0];
    const float* z_imag = (const float*)d_in[1];
    const float* dt     = (const float*)d_in[2];
    const float* w1     = (const float*)d_in[3];
    const float* b1     = (const float*)d_in[4];
    const float* w2     = (const float*)d_in[5];
    const float* b2     = (const float*)d_in[6];

    float* out = (float*)d_out;
    char* ws = (char*)d_ws;
    f16*   w1tb = (f16*)ws;
    float* psi  = (float*)(ws + 73728);

    hipLaunchKernelGGL(k_wt, dim3(144), dim3(256), 0, stream, w1, w1tb);

    if (ws_size >= NEED_FAST) {
        // All gather sources in d_ws; act scratch in d_out (consumed by conv2
        // before k_sample_fast overwrites d_out).
        f16* Xt_r = (f16*)(ws + 73728 + (1u << 20));
        f16* Xt_i = (f16*)((char*)Xt_r + PLANE);
        f16* act  = (f16*)d_out;

        hipLaunchKernelGGL(k_xt, dim3(HWp / 64, 4), dim3(256), 0, stream, z_real, Xt_r);
        hipLaunchKernelGGL(k_xt, dim3(HWp / 64, 4), dim3(256), 0, stream, z_imag, Xt_i);
        hipLaunchKernelGGL(k_conv1, dim3(256, 4), dim3(256), 0, stream, Xt_r, w1tb, b1, act);
        hipLaunchKernelGGL(k_conv2, dim3(8, 32, 4), dim3(256), 0, stream, act, w2, b2, dt, psi);
        hipLaunchKernelGGL(k_sample_fast, dim3(64, 32), dim3(256), 0, stream,
                           Xt_r, Xt_i, psi, out);
    } else {
        // Fallback: round-3 structure (Xt/act scratch inside d_out).
        f16* Xt  = (f16*)d_out;
        f16* act = (f16*)((char*)d_out + PLANE);

        hipLaunchKernelGGL(k_xt, dim3(HWp / 64, 4), dim3(256), 0, stream, z_real, Xt);
        hipLaunchKernelGGL(k_conv1, dim3(256, 4), dim3(256), 0, stream, Xt, w1tb, b1, act);
        hipLaunchKernelGGL(k_conv2, dim3(8, 32, 4), dim3(256), 0, stream, act, w2, b2, dt, psi);
        hipLaunchKernelGGL(k_sample_fb, dim3(8, 32, 32), dim3(256), 0, stream,
                           z_real, z_imag, psi, out);
    }
}

// Round 5
// 239.200 us; speedup vs baseline: 1.0909x; 1.0909x over previous
//
#include <hip/hip_runtime.h>
#include <cmath>

namespace {
constexpr int H = 256, W = 256, HWp = H * W;
constexpr size_t PLANE = (size_t)4 * HWp * 64 * 2;  // one NHWC fp16 tensor
constexpr size_t NEED_FAST = 73728 + (1u << 20) + 2 * PLANE;
}

typedef _Float16 f16;
typedef __attribute__((ext_vector_type(4))) _Float16 f16x4;
typedef __attribute__((ext_vector_type(8))) _Float16 f16x8;
typedef __attribute__((ext_vector_type(4))) float f32x4;
typedef __attribute__((ext_vector_type(4))) unsigned int u32x4;

// K_wt: w1 [co][ci][3][3] fp32 -> w1tb [k9][co][ci] fp16
__global__ void k_wt(const float* __restrict__ w1, f16* __restrict__ w1tb) {
    int i = blockIdx.x * 256 + threadIdx.x;
    if (i >= 64 * 576) return;
    int co = i / 576, r = i - co * 576;
    int ci = r / 9, k9 = r - ci * 9;
    w1tb[(k9 * 64 + co) * 64 + ci] = (f16)w1[i];
}

// K_xt: one 64-ch plane-set NCHW fp32 -> NHWC fp16. float4 reads via LDS.
__global__ __launch_bounds__(256) void k_xt(const float* __restrict__ x,
                                            f16* __restrict__ dst) {
    __shared__ f16 tile[64][80];
    const int t = threadIdx.x;
    const int p0 = blockIdx.x * 64;
    const size_t base = (size_t)blockIdx.y * 64 * HWp;
#pragma unroll
    for (int r = 0; r < 4; ++r) {
        int q = r * 256 + t;
        int ci = q >> 4, px4 = (q & 15) * 4;
        f32x4 v = *reinterpret_cast<const f32x4*>(x + base + (size_t)ci * HWp + p0 + px4);
#pragma unroll
        for (int j = 0; j < 4; ++j) tile[px4 + j][ci] = (f16)v[j];
    }
    __syncthreads();
    const int px = t >> 2, q = t & 3;
    u32x4* d = reinterpret_cast<u32x4*>(dst + ((size_t)blockIdx.y * HWp + p0 + px) * 64 + q * 16);
    const u32x4* s = reinterpret_cast<const u32x4*>(&tile[px][q * 16]);
    d[0] = s[0];
    d[1] = s[1];
}

// K1: conv1 via f16 MFMA, 2-deep register prefetch, XCD-swizzled rows.
// Block = one row (256 px), 4 waves x (64 px, 64 co).
// MFMA operand order: D = W_frag * Px_frag -> D col = px (lane&15),
// row = co_sub (lg*4+reg) -> epilogue stores f16x4 per (m,n), coalesced.
__global__ __launch_bounds__(256, 3) void k_conv1(
        const f16* __restrict__ Xt,    // [B][HWp][64] fp16
        const f16* __restrict__ w1tb,  // [9][64co][64ci] fp16
        const float* __restrict__ b1,
        f16* __restrict__ act) {       // [B][HWp][64] fp16
    const int wid = threadIdx.x >> 6;
    const int lane = threadIdx.x & 63;
    const int lr = lane & 15;
    const int lg = lane >> 4;

    // bijective XCD swizzle: XCD k owns a contiguous 128-row chunk
    const int bid = blockIdx.x;                 // 0..1023
    const int swz = (bid & 7) * 128 + (bid >> 3);
    const int y = swz & 255, b = swz >> 8;

    const int x_base = wid * 64;
    f32x4 acc[4][4];
#pragma unroll
    for (int m = 0; m < 4; ++m)
#pragma unroll
        for (int n = 0; n < 4; ++n) acc[m][n] = (f32x4)0.f;

    const size_t row_base = ((size_t)b * H + y) * W;
    const f16* Arow = Xt + (row_base + x_base + lr) * 64 + lg * 8;
    const f16* Bw = w1tb + lr * 64 + lg * 8;
    const f16x8 zf = (f16x8)(f16)0.f;

    f16x8 Ab[2][4], Wb[2][4];

    auto load_step = [&](int s, f16x8* Adst, f16x8* Wdst) {
        const int k9 = s >> 1, ci0 = (s & 1) * 32;
        const int dy = k9 / 3 - 1, dx = k9 % 3 - 1;
        const bool okr = (unsigned)(y + dy) < 256u;
        const int dyy = okr ? dy : 0;
        const f16* Ar = Arow + (ptrdiff_t)dyy * (W * 64) + ci0;
        const f16* Wk = Bw + k9 * 4096 + ci0;
#pragma unroll
        for (int n = 0; n < 4; ++n)
            Wdst[n] = *reinterpret_cast<const f16x8*>(Wk + n * 1024);
#pragma unroll
        for (int m = 0; m < 4; ++m) {
            const int gx = x_base + m * 16 + lr + dx;
            const bool okc = (unsigned)gx < 256u;
            const int dxx = okc ? dx : 0;
            f16x8 t = *reinterpret_cast<const f16x8*>(Ar + (ptrdiff_t)(m * 16 + dxx) * 64);
            Adst[m] = (okc && okr) ? t : zf;
        }
    };

    load_step(0, Ab[0], Wb[0]);
#pragma unroll
    for (int s = 0; s < 18; ++s) {
        const int cur = s & 1, nxt = cur ^ 1;
        if (s < 17) load_step(s + 1, Ab[nxt], Wb[nxt]);
#pragma unroll
        for (int m = 0; m < 4; ++m)
#pragma unroll
            for (int n = 0; n < 4; ++n)
                acc[m][n] = __builtin_amdgcn_mfma_f32_16x16x32_f16(
                    Wb[cur][n], Ab[cur][m], acc[m][n], 0, 0, 0);
    }

    // Epilogue: lane holds px = m*16+lr, co = n*16+lg*4+r.
    float bias[4][4];
#pragma unroll
    for (int n = 0; n < 4; ++n) {
        f32x4 bv = *reinterpret_cast<const f32x4*>(b1 + n * 16 + lg * 4);
#pragma unroll
        for (int r = 0; r < 4; ++r) bias[n][r] = bv[r];
    }
#pragma unroll
    for (int m = 0; m < 4; ++m) {
        f16* ap = act + (row_base + x_base + m * 16 + lr) * 64 + lg * 4;
#pragma unroll
        for (int n = 0; n < 4; ++n) {
            f16x4 o;
#pragma unroll
            for (int r = 0; r < 4; ++r) {
                float v = acc[m][n][r] + bias[n][r];
                v = v / (1.f + __expf(-v));
                o[r] = (f16)v;
            }
            *reinterpret_cast<f16x4*>(ap + n * 16) = o;
        }
    }
}

// K2: conv2 (64->1) + *dt -> psi. NHWC fp16 input, f16x8 vector loads.
__global__ __launch_bounds__(256) void k_conv2(
        const f16* __restrict__ act, const float* __restrict__ w2,
        const float* __restrict__ b2, const float* __restrict__ dtp,
        float* __restrict__ psi) {
    const int tx = threadIdx.x & 31, ty = threadIdx.x >> 5;
    const int px = blockIdx.x * 32 + tx;
    const int py = blockIdx.y * 8 + ty;
    const int b = blockIdx.z;

    float a0 = 0.f, a1 = 0.f, a2 = 0.f, a3 = 0.f;
#pragma unroll
    for (int dy = -1; dy <= 1; ++dy) {
        const int yy = py + dy;
        if ((unsigned)yy >= (unsigned)H) continue;
#pragma unroll
        for (int dx = -1; dx <= 1; ++dx) {
            const int xx = px + dx;
            const int k9 = (dy + 1) * 3 + (dx + 1);
            if ((unsigned)xx < (unsigned)W) {
                const f16x8* ap = reinterpret_cast<const f16x8*>(
                    act + (((size_t)b * H + yy) * W + xx) * 64);
                const float* wp = w2 + k9;
#pragma unroll
                for (int g = 0; g < 8; ++g) {
                    const f16x8 v = ap[g];
                    const int cb = g * 8;
                    a0 = fmaf((float)v[0], wp[(cb + 0) * 9], a0);
                    a1 = fmaf((float)v[1], wp[(cb + 1) * 9], a1);
                    a2 = fmaf((float)v[2], wp[(cb + 2) * 9], a2);
                    a3 = fmaf((float)v[3], wp[(cb + 3) * 9], a3);
                    a0 = fmaf((float)v[4], wp[(cb + 4) * 9], a0);
                    a1 = fmaf((float)v[5], wp[(cb + 5) * 9], a1);
                    a2 = fmaf((float)v[6], wp[(cb + 6) * 9], a2);
                    a3 = fmaf((float)v[7], wp[(cb + 7) * 9], a3);
                }
            }
        }
    }
    psi[((size_t)b * H + py) * W + px] = ((a0 + a1) + (a2 + a3) + b2[0]) * dtp[0];
}

// K3 fast: curl + bilinear sample from NHWC fp16. Thread = 4 px x 16 ch.
__global__ __launch_bounds__(256) void k_sample_fast(
        const f16* __restrict__ Xt_r, const f16* __restrict__ Xt_i,
        const float* __restrict__ psi, float* __restrict__ out) {
    const int lane = threadIdx.x & 63;
    const int y = blockIdx.x * 4 + (threadIdx.x >> 6);
    const int b = blockIdx.y >> 3;
    const int cg = blockIdx.y & 7;
    const int px0 = lane * 4;

    const f16* src = ((cg < 4) ? Xt_r : Xt_i) + (size_t)b * HWp * 64 + (cg & 3) * 16;
    const float* pb = psi + b * HWp;

    f32x4 outv[16];
#pragma unroll
    for (int i = 0; i < 4; ++i) {
        const int px = px0 + i;
        const int yp = min(y + 1, H - 1), ym = max(y - 1, 0);
        const int xp = min(px + 1, W - 1), xm = max(px - 1, 0);
        const float u = 0.5f * (pb[yp * W + px] - pb[ym * W + px]);
        const float v = -0.5f * (pb[y * W + xp] - pb[y * W + xm]);

        const float gx = (-1.f + 2.f * px / (float)(W - 1)) - u * (2.f / (float)W);
        const float gy = (-1.f + 2.f * y / (float)(H - 1)) - v * (2.f / (float)H);

        float ix = fminf(fmaxf((gx + 1.f) * 0.5f * (float)(W - 1), 0.f), (float)(W - 1));
        float iy = fminf(fmaxf((gy + 1.f) * 0.5f * (float)(H - 1), 0.f), (float)(H - 1));
        const float xf = floorf(ix), yf = floorf(iy);
        const float wx = ix - xf, wy = iy - yf;
        const int ix0 = (int)xf, iy0 = (int)yf;
        const int ix1 = min(ix0 + 1, W - 1), iy1 = min(iy0 + 1, H - 1);

        const float w00 = (1.f - wx) * (1.f - wy), w01 = wx * (1.f - wy);
        const float w10 = (1.f - wx) * wy, w11 = wx * wy;

        const f16x8* p00 = reinterpret_cast<const f16x8*>(src + (size_t)(iy0 * W + ix0) * 64);
        const f16x8* p01 = reinterpret_cast<const f16x8*>(src + (size_t)(iy0 * W + ix1) * 64);
        const f16x8* p10 = reinterpret_cast<const f16x8*>(src + (size_t)(iy1 * W + ix0) * 64);
        const f16x8* p11 = reinterpret_cast<const f16x8*>(src + (size_t)(iy1 * W + ix1) * 64);
        const f16x8 h00a = p00[0], h00b = p00[1];
        const f16x8 h01a = p01[0], h01b = p01[1];
        const f16x8 h10a = p10[0], h10b = p10[1];
        const f16x8 h11a = p11[0], h11b = p11[1];
#pragma unroll
        for (int c = 0; c < 8; ++c)
            outv[c][i] = (float)h00a[c] * w00 + (float)h01a[c] * w01 +
                         (float)h10a[c] * w10 + (float)h11a[c] * w11;
#pragma unroll
        for (int c = 0; c < 8; ++c)
            outv[8 + c][i] = (float)h00b[c] * w00 + (float)h01b[c] * w01 +
                             (float)h10b[c] * w10 + (float)h11b[c] * w11;
    }

    float* ob = out + ((size_t)b * 128 + cg * 16) * HWp + y * W + px0;
#pragma unroll
    for (int c = 0; c < 16; ++c)
        *reinterpret_cast<f32x4*>(ob + (size_t)c * HWp) = outv[c];
}

// K3 fallback: scalar gather from fp32 NCHW.
__global__ __launch_bounds__(256) void k_sample_fb(
        const float* __restrict__ zr, const float* __restrict__ zi,
        const float* __restrict__ psi, float* __restrict__ out) {
    const int tx = threadIdx.x & 31, ty = threadIdx.x >> 5;
    const int px = blockIdx.x * 32 + tx;
    const int py = blockIdx.y * 8 + ty;
    const int b  = blockIdx.z >> 3;
    const int c0 = (blockIdx.z & 7) * 16;

    const float* pb = psi + b * HWp;
    const int yp = min(py + 1, H - 1), ym = max(py - 1, 0);
    const int xp = min(px + 1, W - 1), xm = max(px - 1, 0);
    const float u = 0.5f * (pb[yp * W + px] - pb[ym * W + px]);
    const float v = -0.5f * (pb[py * W + xp] - pb[py * W + xm]);

    const float gx = (-1.f + 2.f * px / (float)(W - 1)) - u * (2.f / (float)W);
    const float gy = (-1.f + 2.f * py / (float)(H - 1)) - v * (2.f / (float)H);

    float ix = fminf(fmaxf((gx + 1.f) * 0.5f * (float)(W - 1), 0.f), (float)(W - 1));
    float iy = fminf(fmaxf((gy + 1.f) * 0.5f * (float)(H - 1), 0.f), (float)(H - 1));
    const float xf = floorf(ix), yf = floorf(iy);
    const float wx = ix - xf, wy = iy - yf;
    const int ix0 = (int)xf, iy0 = (int)yf;
    const int ix1 = min(ix0 + 1, W - 1), iy1 = min(iy0 + 1, H - 1);

    const int o00 = iy0 * W + ix0, o01 = iy0 * W + ix1;
    const int o10 = iy1 * W + ix0, o11 = iy1 * W + ix1;
    const float w00 = (1.f - wx) * (1.f - wy), w01 = wx * (1.f - wy);
    const float w10 = (1.f - wx) * wy, w11 = wx * wy;

    const float* src0 = (c0 < 64) ? (zr + (size_t)b * 64 * HWp + (size_t)c0 * HWp)
                                  : (zi + (size_t)b * 64 * HWp + (size_t)(c0 - 64) * HWp);
    float* ob = out + ((size_t)b * 128 + c0) * HWp + py * W + px;
#pragma unroll
    for (int c = 0; c < 16; ++c) {
        const float* p = src0 + (size_t)c * HWp;
        ob[(size_t)c * HWp] = p[o00] * w00 + p[o01] * w01 + p[o10] * w10 + p[o11] * w11;
    }
}

extern "C" void kernel_launch(void* const* d_in, const int* in_sizes, int n_in,
                              void* d_out, int out_size, void* d_ws, size_t ws_size,
                              hipStream_t stream) {
    const float* z_real = (const float*)d_in[0];
    const float* z_imag = (const float*)d_in[1];
    const float* dt     = (const float*)d_in[2];
    const float* w1     = (const float*)d_in[3];
    const float* b1     = (const float*)d_in[4];
    const float* w2     = (const float*)d_in[5];
    const float* b2     = (const float*)d_in[6];

    float* out = (float*)d_out;
    char* ws = (char*)d_ws;
    f16*   w1tb = (f16*)ws;
    float* psi  = (float*)(ws + 73728);

    hipLaunchKernelGGL(k_wt, dim3(144), dim3(256), 0, stream, w1, w1tb);

    if (ws_size >= NEED_FAST) {
        f16* Xt_r = (f16*)(ws + 73728 + (1u << 20));
        f16* Xt_i = (f16*)((char*)Xt_r + PLANE);
        f16* act  = (f16*)d_out;

        hipLaunchKernelGGL(k_xt, dim3(HWp / 64, 4), dim3(256), 0, stream, z_real, Xt_r);
        hipLaunchKernelGGL(k_xt, dim3(HWp / 64, 4), dim3(256), 0, stream, z_imag, Xt_i);
        hipLaunchKernelGGL(k_conv1, dim3(1024), dim3(256), 0, stream, Xt_r, w1tb, b1, act);
        hipLaunchKernelGGL(k_conv2, dim3(8, 32, 4), dim3(256), 0, stream, act, w2, b2, dt, psi);
        hipLaunchKernelGGL(k_sample_fast, dim3(64, 32), dim3(256), 0, stream,
                           Xt_r, Xt_i, psi, out);
    } else {
        f16* Xt  = (f16*)d_out;
        f16* act = (f16*)((char*)d_out + PLANE);

        hipLaunchKernelGGL(k_xt, dim3(HWp / 64, 4), dim3(256), 0, stream, z_real, Xt);
        hipLaunchKernelGGL(k_conv1, dim3(1024), dim3(256), 0, stream, Xt, w1tb, b1, act);
        hipLaunchKernelGGL(k_conv2, dim3(8, 32, 4), dim3(256), 0, stream, act, w2, b2, dt, psi);
        hipLaunchKernelGGL(k_sample_fb, dim3(8, 32, 32), dim3(256), 0, stream,
                           z_real, z_imag, psi, out);
    }
}

// Round 6
// 236.932 us; speedup vs baseline: 1.1013x; 1.0096x over previous
//
#include <hip/hip_runtime.h>
#include <cmath>

namespace {
constexpr int H = 256, W = 256, HWp = H * W;
constexpr size_t PLANE = (size_t)4 * HWp * 64 * 2;  // one NHWC fp16 tensor
constexpr size_t NEED_FAST = 73728 + (1u << 20) + 2 * PLANE;
}

typedef _Float16 f16;
typedef __attribute__((ext_vector_type(4))) _Float16 f16x4;
typedef __attribute__((ext_vector_type(8))) _Float16 f16x8;
typedef __attribute__((ext_vector_type(4))) float f32x4;
typedef __attribute__((ext_vector_type(4))) unsigned int u32x4;

// K_wt: w1 [co][ci][3][3] fp32 -> w1tb [k9][co][ci] fp16
__global__ void k_wt(const float* __restrict__ w1, f16* __restrict__ w1tb) {
    int i = blockIdx.x * 256 + threadIdx.x;
    if (i >= 64 * 576) return;
    int co = i / 576, r = i - co * 576;
    int ci = r / 9, k9 = r - ci * 9;
    w1tb[(k9 * 64 + co) * 64 + ci] = (f16)w1[i];
}

// K_xt: one 64-ch plane-set NCHW fp32 -> NHWC fp16. float4 reads via LDS.
__global__ __launch_bounds__(256) void k_xt(const float* __restrict__ x,
                                            f16* __restrict__ dst) {
    __shared__ f16 tile[64][80];
    const int t = threadIdx.x;
    const int p0 = blockIdx.x * 64;
    const size_t base = (size_t)blockIdx.y * 64 * HWp;
#pragma unroll
    for (int r = 0; r < 4; ++r) {
        int q = r * 256 + t;
        int ci = q >> 4, px4 = (q & 15) * 4;
        f32x4 v = *reinterpret_cast<const f32x4*>(x + base + (size_t)ci * HWp + p0 + px4);
#pragma unroll
        for (int j = 0; j < 4; ++j) tile[px4 + j][ci] = (f16)v[j];
    }
    __syncthreads();
    const int px = t >> 2, q = t & 3;
    u32x4* d = reinterpret_cast<u32x4*>(dst + ((size_t)blockIdx.y * HWp + p0 + px) * 64 + q * 16);
    const u32x4* s = reinterpret_cast<const u32x4*>(&tile[px][q * 16]);
    d[0] = s[0];
    d[1] = s[1];
}

// ---- conv1 statically-indexed pipeline helpers ----
template<int S>
__device__ __forceinline__ void c1_load(
        const f16* __restrict__ Arow, const f16* __restrict__ Bw,
        int y, int x_base, int lr,
        f16x8& A0, f16x8& A1, f16x8& A2, f16x8& A3,
        f16x8& W0, f16x8& W1, f16x8& W2, f16x8& W3) {
    constexpr int k9 = S >> 1, ci0 = (S & 1) * 32;
    constexpr int dy = k9 / 3 - 1, dx = k9 % 3 - 1;
    const bool okr = (unsigned)(y + dy) < 256u;
    const f16* Ar = Arow + (ptrdiff_t)(okr ? dy : 0) * (256 * 64) + ci0;
    const f16* Wk = Bw + k9 * 4096 + ci0;
    W0 = *reinterpret_cast<const f16x8*>(Wk);
    W1 = *reinterpret_cast<const f16x8*>(Wk + 1024);
    W2 = *reinterpret_cast<const f16x8*>(Wk + 2048);
    W3 = *reinterpret_cast<const f16x8*>(Wk + 3072);
    const f16x8 zf = (f16x8)(f16)0.f;
#define C1_A(mm, DST) { \
        const int gx = x_base + mm * 16 + lr + dx; \
        const bool ok = okr && ((unsigned)gx < 256u); \
        f16x8 t = *reinterpret_cast<const f16x8*>( \
            Ar + (ptrdiff_t)(mm * 16 + (ok ? dx : 0)) * 64); \
        DST = ok ? t : zf; }
    C1_A(0, A0) C1_A(1, A1) C1_A(2, A2) C1_A(3, A3)
#undef C1_A
}

#define C1_MFMA_ONE(Wv, Av, M, N) \
    acc[M][N] = __builtin_amdgcn_mfma_f32_16x16x32_f16(Wv, Av, acc[M][N], 0, 0, 0);
#define C1_MFMA(A0_,A1_,A2_,A3_,W0_,W1_,W2_,W3_) \
    C1_MFMA_ONE(W0_,A0_,0,0) C1_MFMA_ONE(W1_,A0_,0,1) C1_MFMA_ONE(W2_,A0_,0,2) C1_MFMA_ONE(W3_,A0_,0,3) \
    C1_MFMA_ONE(W0_,A1_,1,0) C1_MFMA_ONE(W1_,A1_,1,1) C1_MFMA_ONE(W2_,A1_,1,2) C1_MFMA_ONE(W3_,A1_,1,3) \
    C1_MFMA_ONE(W0_,A2_,2,0) C1_MFMA_ONE(W1_,A2_,2,1) C1_MFMA_ONE(W2_,A2_,2,2) C1_MFMA_ONE(W3_,A2_,2,3) \
    C1_MFMA_ONE(W0_,A3_,3,0) C1_MFMA_ONE(W1_,A3_,3,1) C1_MFMA_ONE(W2_,A3_,3,2) C1_MFMA_ONE(W3_,A3_,3,3)

#define LOADS(S, T) c1_load<S>(Arow, Bw, y, x_base, lr, \
    a##T##0, a##T##1, a##T##2, a##T##3, w##T##0, w##T##1, w##T##2, w##T##3);
#define MF(T) C1_MFMA(a##T##0, a##T##1, a##T##2, a##T##3, w##T##0, w##T##1, w##T##2, w##T##3)

// K1: conv1 via f16 MFMA, 3-set named register pipeline, XCD-swizzled rows.
// D = W_frag * Px_frag -> D col = px (lane&15), row = co_sub (lg*4+reg).
__global__ __launch_bounds__(256, 2) void k_conv1(
        const f16* __restrict__ Xt,    // [B][HWp][64] fp16
        const f16* __restrict__ w1tb,  // [9][64co][64ci] fp16
        const float* __restrict__ b1,
        f16* __restrict__ act) {       // [B][HWp][64] fp16
    const int wid = threadIdx.x >> 6;
    const int lane = threadIdx.x & 63;
    const int lr = lane & 15;
    const int lg = lane >> 4;

    const int bid = blockIdx.x;                 // 0..1023
    const int swz = (bid & 7) * 128 + (bid >> 3);
    const int y = swz & 255, b = swz >> 8;

    const int x_base = wid * 64;
    f32x4 acc[4][4];
#pragma unroll
    for (int m = 0; m < 4; ++m)
#pragma unroll
        for (int n = 0; n < 4; ++n) acc[m][n] = (f32x4)0.f;

    const size_t row_base = ((size_t)b * H + y) * W;
    const f16* Arow = Xt + (row_base + x_base + lr) * 64 + lg * 8;
    const f16* Bw = w1tb + lr * 64 + lg * 8;

    f16x8 a00, a01, a02, a03, w00, w01, w02, w03;
    f16x8 a10, a11, a12, a13, w10, w11, w12, w13;
    f16x8 a20, a21, a22, a23, w20, w21, w22, w23;

    LOADS(0, 0) LOADS(1, 1)
    MF(0) LOADS(2, 2)
    MF(1) LOADS(3, 0)
    MF(2) LOADS(4, 1)
    MF(0) LOADS(5, 2)
    MF(1) LOADS(6, 0)
    MF(2) LOADS(7, 1)
    MF(0) LOADS(8, 2)
    MF(1) LOADS(9, 0)
    MF(2) LOADS(10, 1)
    MF(0) LOADS(11, 2)
    MF(1) LOADS(12, 0)
    MF(2) LOADS(13, 1)
    MF(0) LOADS(14, 2)
    MF(1) LOADS(15, 0)
    MF(2) LOADS(16, 1)
    MF(0) LOADS(17, 2)
    MF(1)
    MF(2)

    // Epilogue: lane holds px = m*16+lr, co = n*16+lg*4+r.
    float bias[4][4];
#pragma unroll
    for (int n = 0; n < 4; ++n) {
        f32x4 bv = *reinterpret_cast<const f32x4*>(b1 + n * 16 + lg * 4);
#pragma unroll
        for (int r = 0; r < 4; ++r) bias[n][r] = bv[r];
    }
#pragma unroll
    for (int m = 0; m < 4; ++m) {
        f16* ap = act + (row_base + x_base + m * 16 + lr) * 64 + lg * 4;
#pragma unroll
        for (int n = 0; n < 4; ++n) {
            f16x4 o;
#pragma unroll
            for (int r = 0; r < 4; ++r) {
                float v = acc[m][n][r] + bias[n][r];
                v = v / (1.f + __expf(-v));
                o[r] = (f16)v;
            }
            *reinterpret_cast<f16x4*>(ap + n * 16) = o;
        }
    }
}

// K2: conv2 (64->1) + *dt -> psi. NHWC fp16 input, f16x8 vector loads.
__global__ __launch_bounds__(256) void k_conv2(
        const f16* __restrict__ act, const float* __restrict__ w2,
        const float* __restrict__ b2, const float* __restrict__ dtp,
        float* __restrict__ psi) {
    const int tx = threadIdx.x & 31, ty = threadIdx.x >> 5;
    const int px = blockIdx.x * 32 + tx;
    const int py = blockIdx.y * 8 + ty;
    const int b = blockIdx.z;

    float a0 = 0.f, a1 = 0.f, a2 = 0.f, a3 = 0.f;
#pragma unroll
    for (int dy = -1; dy <= 1; ++dy) {
        const int yy = py + dy;
        if ((unsigned)yy >= (unsigned)H) continue;
#pragma unroll
        for (int dx = -1; dx <= 1; ++dx) {
            const int xx = px + dx;
            const int k9 = (dy + 1) * 3 + (dx + 1);
            if ((unsigned)xx < (unsigned)W) {
                const f16x8* ap = reinterpret_cast<const f16x8*>(
                    act + (((size_t)b * H + yy) * W + xx) * 64);
                const float* wp = w2 + k9;
#pragma unroll
                for (int g = 0; g < 8; ++g) {
                    const f16x8 v = ap[g];
                    const int cb = g * 8;
                    a0 = fmaf((float)v[0], wp[(cb + 0) * 9], a0);
                    a1 = fmaf((float)v[1], wp[(cb + 1) * 9], a1);
                    a2 = fmaf((float)v[2], wp[(cb + 2) * 9], a2);
                    a3 = fmaf((float)v[3], wp[(cb + 3) * 9], a3);
                    a0 = fmaf((float)v[4], wp[(cb + 4) * 9], a0);
                    a1 = fmaf((float)v[5], wp[(cb + 5) * 9], a1);
                    a2 = fmaf((float)v[6], wp[(cb + 6) * 9], a2);
                    a3 = fmaf((float)v[7], wp[(cb + 7) * 9], a3);
                }
            }
        }
    }
    psi[((size_t)b * H + py) * W + px] = ((a0 + a1) + (a2 + a3) + b2[0]) * dtp[0];
}

// K3 fast: curl + bilinear sample from NHWC fp16. Thread = 4 px x 16 ch.
__global__ __launch_bounds__(256) void k_sample_fast(
        const f16* __restrict__ Xt_r, const f16* __restrict__ Xt_i,
        const float* __restrict__ psi, float* __restrict__ out) {
    const int lane = threadIdx.x & 63;
    const int y = blockIdx.x * 4 + (threadIdx.x >> 6);
    const int b = blockIdx.y >> 3;
    const int cg = blockIdx.y & 7;
    const int px0 = lane * 4;

    const f16* src = ((cg < 4) ? Xt_r : Xt_i) + (size_t)b * HWp * 64 + (cg & 3) * 16;
    const float* pb = psi + b * HWp;

    f32x4 outv[16];
#pragma unroll
    for (int i = 0; i < 4; ++i) {
        const int px = px0 + i;
        const int yp = min(y + 1, H - 1), ym = max(y - 1, 0);
        const int xp = min(px + 1, W - 1), xm = max(px - 1, 0);
        const float u = 0.5f * (pb[yp * W + px] - pb[ym * W + px]);
        const float v = -0.5f * (pb[y * W + xp] - pb[y * W + xm]);

        const float gx = (-1.f + 2.f * px / (float)(W - 1)) - u * (2.f / (float)W);
        const float gy = (-1.f + 2.f * y / (float)(H - 1)) - v * (2.f / (float)H);

        float ix = fminf(fmaxf((gx + 1.f) * 0.5f * (float)(W - 1), 0.f), (float)(W - 1));
        float iy = fminf(fmaxf((gy + 1.f) * 0.5f * (float)(H - 1), 0.f), (float)(H - 1));
        const float xf = floorf(ix), yf = floorf(iy);
        const float wx = ix - xf, wy = iy - yf;
        const int ix0 = (int)xf, iy0 = (int)yf;
        const int ix1 = min(ix0 + 1, W - 1), iy1 = min(iy0 + 1, H - 1);

        const float w00 = (1.f - wx) * (1.f - wy), w01 = wx * (1.f - wy);
        const float w10 = (1.f - wx) * wy, w11 = wx * wy;

        const f16x8* p00 = reinterpret_cast<const f16x8*>(src + (size_t)(iy0 * W + ix0) * 64);
        const f16x8* p01 = reinterpret_cast<const f16x8*>(src + (size_t)(iy0 * W + ix1) * 64);
        const f16x8* p10 = reinterpret_cast<const f16x8*>(src + (size_t)(iy1 * W + ix0) * 64);
        const f16x8* p11 = reinterpret_cast<const f16x8*>(src + (size_t)(iy1 * W + ix1) * 64);
        const f16x8 h00a = p00[0], h00b = p00[1];
        const f16x8 h01a = p01[0], h01b = p01[1];
        const f16x8 h10a = p10[0], h10b = p10[1];
        const f16x8 h11a = p11[0], h11b = p11[1];
#pragma unroll
        for (int c = 0; c < 8; ++c)
            outv[c][i] = (float)h00a[c] * w00 + (float)h01a[c] * w01 +
                         (float)h10a[c] * w10 + (float)h11a[c] * w11;
#pragma unroll
        for (int c = 0; c < 8; ++c)
            outv[8 + c][i] = (float)h00b[c] * w00 + (float)h01b[c] * w01 +
                             (float)h10b[c] * w10 + (float)h11b[c] * w11;
    }

    float* ob = out + ((size_t)b * 128 + cg * 16) * HWp + y * W + px0;
#pragma unroll
    for (int c = 0; c < 16; ++c)
        *reinterpret_cast<f32x4*>(ob + (size_t)c * HWp) = outv[c];
}

// K3 fallback: scalar gather from fp32 NCHW.
__global__ __launch_bounds__(256) void k_sample_fb(
        const float* __restrict__ zr, const float* __restrict__ zi,
        const float* __restrict__ psi, float* __restrict__ out) {
    const int tx = threadIdx.x & 31, ty = threadIdx.x >> 5;
    const int px = blockIdx.x * 32 + tx;
    const int py = blockIdx.y * 8 + ty;
    const int b  = blockIdx.z >> 3;
    const int c0 = (blockIdx.z & 7) * 16;

    const float* pb = psi + b * HWp;
    const int yp = min(py + 1, H - 1), ym = max(py - 1, 0);
    const int xp = min(px + 1, W - 1), xm = max(px - 1, 0);
    const float u = 0.5f * (pb[yp * W + px] - pb[ym * W + px]);
    const float v = -0.5f * (pb[py * W + xp] - pb[py * W + xm]);

    const float gx = (-1.f + 2.f * px / (float)(W - 1)) - u * (2.f / (float)W);
    const float gy = (-1.f + 2.f * py / (float)(H - 1)) - v * (2.f / (float)H);

    float ix = fminf(fmaxf((gx + 1.f) * 0.5f * (float)(W - 1), 0.f), (float)(W - 1));
    float iy = fminf(fmaxf((gy + 1.f) * 0.5f * (float)(H - 1), 0.f), (float)(H - 1));
    const float xf = floorf(ix), yf = floorf(iy);
    const float wx = ix - xf, wy = iy - yf;
    const int ix0 = (int)xf, iy0 = (int)yf;
    const int ix1 = min(ix0 + 1, W - 1), iy1 = min(iy0 + 1, H - 1);

    const int o00 = iy0 * W + ix0, o01 = iy0 * W + ix1;
    const int o10 = iy1 * W + ix0, o11 = iy1 * W + ix1;
    const float w00 = (1.f - wx) * (1.f - wy), w01 = wx * (1.f - wy);
    const float w10 = (1.f - wx) * wy, w11 = wx * wy;

    const float* src0 = (c0 < 64) ? (zr + (size_t)b * 64 * HWp + (size_t)c0 * HWp)
                                  : (zi + (size_t)b * 64 * HWp + (size_t)(c0 - 64) * HWp);
    float* ob = out + ((size_t)b * 128 + c0) * HWp + py * W + px;
#pragma unroll
    for (int c = 0; c < 16; ++c) {
        const float* p = src0 + (size_t)c * HWp;
        ob[(size_t)c * HWp] = p[o00] * w00 + p[o01] * w01 + p[o10] * w10 + p[o11] * w11;
    }
}

extern "C" void kernel_launch(void* const* d_in, const int* in_sizes, int n_in,
                              void* d_out, int out_size, void* d_ws, size_t ws_size,
                              hipStream_t stream) {
    const float* z_real = (const float*)d_in[0];
    const float* z_imag = (const float*)d_in[1];
    const float* dt     = (const float*)d_in[2];
    const float* w1     = (const float*)d_in[3];
    const float* b1     = (const float*)d_in[4];
    const float* w2     = (const float*)d_in[5];
    const float* b2     = (const float*)d_in[6];

    float* out = (float*)d_out;
    char* ws = (char*)d_ws;
    f16*   w1tb = (f16*)ws;
    float* psi  = (float*)(ws + 73728);

    hipLaunchKernelGGL(k_wt, dim3(144), dim3(256), 0, stream, w1, w1tb);

    if (ws_size >= NEED_FAST) {
        f16* Xt_r = (f16*)(ws + 73728 + (1u << 20));
        f16* Xt_i = (f16*)((char*)Xt_r + PLANE);
        f16* act  = (f16*)d_out;

        hipLaunchKernelGGL(k_xt, dim3(HWp / 64, 4), dim3(256), 0, stream, z_real, Xt_r);
        hipLaunchKernelGGL(k_xt, dim3(HWp / 64, 4), dim3(256), 0, stream, z_imag, Xt_i);
        hipLaunchKernelGGL(k_conv1, dim3(1024), dim3(256), 0, stream, Xt_r, w1tb, b1, act);
        hipLaunchKernelGGL(k_conv2, dim3(8, 32, 4), dim3(256), 0, stream, act, w2, b2, dt, psi);
        hipLaunchKernelGGL(k_sample_fast, dim3(64, 32), dim3(256), 0, stream,
                           Xt_r, Xt_i, psi, out);
    } else {
        f16* Xt  = (f16*)d_out;
        f16* act = (f16*)((char*)d_out + PLANE);

        hipLaunchKernelGGL(k_xt, dim3(HWp / 64, 4), dim3(256), 0, stream, z_real, Xt);
        hipLaunchKernelGGL(k_conv1, dim3(1024), dim3(256), 0, stream, Xt, w1tb, b1, act);
        hipLaunchKernelGGL(k_conv2, dim3(8, 32, 4), dim3(256), 0, stream, act, w2, b2, dt, psi);
        hipLaunchKernelGGL(k_sample_fb, dim3(8, 32, 32), dim3(256), 0, stream,
                           z_real, z_imag, psi, out);
    }
}

// Round 7
// 203.198 us; speedup vs baseline: 1.2842x; 1.1660x over previous
//
#include <hip/hip_runtime.h>
#include <cmath>

namespace {
constexpr int H = 256, W = 256, HWp = H * W;
constexpr size_t PLANE = (size_t)4 * HWp * 64 * 2;  // one NHWC fp16 tensor, bytes
constexpr size_t NEED_FAST = 73728 + 2 * PLANE + (1u << 20);
}

typedef _Float16 f16;
typedef unsigned int u32;
typedef __attribute__((ext_vector_type(4))) _Float16 f16x4;
typedef __attribute__((ext_vector_type(8))) _Float16 f16x8;
typedef __attribute__((ext_vector_type(4))) float f32x4;
typedef __attribute__((ext_vector_type(4))) unsigned int u32x4;

__device__ __forceinline__ void dma16(const char* g, char* l) {
    __builtin_amdgcn_global_load_lds(
        (const __attribute__((address_space(1))) u32*)g,
        (__attribute__((address_space(3))) u32*)l, 16, 0, 0);
}

// K_wt: w1 [co][ci][3][3] fp32 -> w1tb [k9][co][ci] fp16
__global__ void k_wt(const float* __restrict__ w1, f16* __restrict__ w1tb) {
    int i = blockIdx.x * 256 + threadIdx.x;
    if (i >= 64 * 576) return;
    int co = i / 576, r = i - co * 576;
    int ci = r / 9, k9 = r - ci * 9;
    w1tb[(k9 * 64 + co) * 64 + ci] = (f16)w1[i];
}

// K_xt: one 64-ch plane-set NCHW fp32 -> NHWC fp16. float4 reads via LDS.
__global__ __launch_bounds__(256) void k_xt(const float* __restrict__ x,
                                            f16* __restrict__ dst) {
    __shared__ f16 tile[64][80];
    const int t = threadIdx.x;
    const int p0 = blockIdx.x * 64;
    const size_t base = (size_t)blockIdx.y * 64 * HWp;
#pragma unroll
    for (int r = 0; r < 4; ++r) {
        int q = r * 256 + t;
        int ci = q >> 4, px4 = (q & 15) * 4;
        f32x4 v = *reinterpret_cast<const f32x4*>(x + base + (size_t)ci * HWp + p0 + px4);
#pragma unroll
        for (int j = 0; j < 4; ++j) tile[px4 + j][ci] = (f16)v[j];
    }
    __syncthreads();
    const int px = t >> 2, q = t & 3;
    u32x4* d = reinterpret_cast<u32x4*>(dst + ((size_t)blockIdx.y * HWp + p0 + px) * 64 + q * 16);
    const u32x4* s = reinterpret_cast<const u32x4*>(&tile[px][q * 16]);
    d[0] = s[0];
    d[1] = s[1];
}

// K1: conv1 via MFMA, LDS-staged (global_load_lds) with XOR-swizzled layout.
// Block = 1 row x 128 px x 64 co; 4 waves (2 px-groups x 2 co-groups).
// Per dy: stage A row (144px halo, 18KB) + W slice (3 k9, 24KB); 6 compute
// steps of 6 ds_read_b128 + 8 MFMA. acc[m][n]: col(px)=lane&15, row(co)=lg*4+r.
__global__ __launch_bounds__(256, 2) void k_conv1(
        const f16* __restrict__ Xt,    // [B][HWp][64] fp16
        const f16* __restrict__ w1tb,  // [9][64co][64ci] fp16
        const float* __restrict__ b1,
        f16* __restrict__ act) {       // [B][HWp][64] fp16
    __shared__ __align__(16) char lds[43008];
    constexpr int WOFF = 18432;

    const int tid = threadIdx.x;
    const int lane = tid & 63, wid = tid >> 6;
    const int lr = lane & 15, lg = lane >> 4;
    const int wpx = wid & 1, wco = wid >> 1;

    // bijective XCD swizzle: each XCD gets 256 consecutive (b,y,xh) units
    const int bid = blockIdx.x;                  // 0..2047
    const int swz = (bid & 7) * 256 + (bid >> 3);
    const int b = swz >> 9;
    const int y = (swz >> 1) & 255;
    const int x0 = (swz & 1) << 7;

    // per-lane swizzled source offset (bytes): granule l -> l ^ ((l>>3)&7)
    const int swzb = (lane ^ ((lane >> 3) & 7)) << 4;

    f32x4 acc[4][2];
#pragma unroll
    for (int m = 0; m < 4; ++m)
#pragma unroll
        for (int n = 0; n < 2; ++n) acc[m][n] = (f32x4)0.f;

    const f16x8 zf = (f16x8)(f16)0.f;

    for (int dyi = 0; dyi < 3; ++dyi) {
        const int yy = y + dyi - 1;
        if ((unsigned)yy >= 256u) continue;      // block-uniform zero-pad skip

        __syncthreads();                          // protect LDS from prev compute
        {
            const char* asrc = (const char*)Xt +
                ((((size_t)b * 256 + yy) * 256 + x0 - 8) * 128) + swzb;
            const char* wsrc = (const char*)w1tb + dyi * 24576 + swzb;
            for (int j = wid; j < 42; j += 4) {
                if (j < 18) dma16(asrc + j * 1024, lds + j * 1024);
                else        dma16(wsrc + (j - 18) * 1024, lds + WOFF + (j - 18) * 1024);
            }
        }
        __syncthreads();                          // drains DMA (vmcnt) + barrier

#pragma unroll
        for (int kx = 0; kx < 3; ++kx) {
            const int dx = kx - 1;
            const int gx0 = x0 + wpx * 64 + lr + dx;        // m=0 pixel
            const bool ok0 = (unsigned)gx0 < 256u;          // fails only dx=-1 edge
            const bool ok3 = (unsigned)(gx0 + 48) < 256u;   // fails only dx=+1 edge
            const int arow = (8 + wpx * 64 + lr + dx) << 7;
            const int axor = (lr + dx) & 7;
#pragma unroll
            for (int c = 0; c < 2; ++c) {
                const int abase = arow + (((c * 4 + lg) ^ axor) << 4);
                f16x8 A0 = *reinterpret_cast<const f16x8*>(lds + abase);
                f16x8 A1 = *reinterpret_cast<const f16x8*>(lds + abase + 2048);
                f16x8 A2 = *reinterpret_cast<const f16x8*>(lds + abase + 4096);
                f16x8 A3 = *reinterpret_cast<const f16x8*>(lds + abase + 6144);
                const int wbase = WOFF + ((kx * 64 + wco * 32 + lr) << 7)
                                + (((c * 4 + lg) ^ (lr & 7)) << 4);
                f16x8 W0 = *reinterpret_cast<const f16x8*>(lds + wbase);
                f16x8 W1 = *reinterpret_cast<const f16x8*>(lds + wbase + 2048);
                A0 = ok0 ? A0 : zf;
                A3 = ok3 ? A3 : zf;
                acc[0][0] = __builtin_amdgcn_mfma_f32_16x16x32_f16(W0, A0, acc[0][0], 0, 0, 0);
                acc[0][1] = __builtin_amdgcn_mfma_f32_16x16x32_f16(W1, A0, acc[0][1], 0, 0, 0);
                acc[1][0] = __builtin_amdgcn_mfma_f32_16x16x32_f16(W0, A1, acc[1][0], 0, 0, 0);
                acc[1][1] = __builtin_amdgcn_mfma_f32_16x16x32_f16(W1, A1, acc[1][1], 0, 0, 0);
                acc[2][0] = __builtin_amdgcn_mfma_f32_16x16x32_f16(W0, A2, acc[2][0], 0, 0, 0);
                acc[2][1] = __builtin_amdgcn_mfma_f32_16x16x32_f16(W1, A2, acc[2][1], 0, 0, 0);
                acc[3][0] = __builtin_amdgcn_mfma_f32_16x16x32_f16(W0, A3, acc[3][0], 0, 0, 0);
                acc[3][1] = __builtin_amdgcn_mfma_f32_16x16x32_f16(W1, A3, acc[3][1], 0, 0, 0);
            }
        }
    }

    // Epilogue: px = x0+wpx*64+m*16+lr, co = wco*32+n*16+lg*4+r.
    float bias[2][4];
#pragma unroll
    for (int n = 0; n < 2; ++n) {
        f32x4 bv = *reinterpret_cast<const f32x4*>(b1 + wco * 32 + n * 16 + lg * 4);
#pragma unroll
        for (int r = 0; r < 4; ++r) bias[n][r] = bv[r];
    }
    const size_t row_base = ((size_t)b * 256 + y) * 256;
#pragma unroll
    for (int m = 0; m < 4; ++m) {
        f16* ap = act + (row_base + x0 + wpx * 64 + m * 16 + lr) * 64 + wco * 32 + lg * 4;
#pragma unroll
        for (int n = 0; n < 2; ++n) {
            f16x4 o;
#pragma unroll
            for (int r = 0; r < 4; ++r) {
                float v = acc[m][n][r] + bias[n][r];
                v = v / (1.f + __expf(-v));
                o[r] = (f16)v;
            }
            *reinterpret_cast<f16x4*>(ap + n * 16) = o;
        }
    }
}

// K2: conv2 (64->1) + *dt -> psi. NHWC fp16 input, f16x8 vector loads.
__global__ __launch_bounds__(256) void k_conv2(
        const f16* __restrict__ act, const float* __restrict__ w2,
        const float* __restrict__ b2, const float* __restrict__ dtp,
        float* __restrict__ psi) {
    const int tx = threadIdx.x & 31, ty = threadIdx.x >> 5;
    const int px = blockIdx.x * 32 + tx;
    const int py = blockIdx.y * 8 + ty;
    const int b = blockIdx.z;

    float a0 = 0.f, a1 = 0.f, a2 = 0.f, a3 = 0.f;
#pragma unroll
    for (int dy = -1; dy <= 1; ++dy) {
        const int yy = py + dy;
        if ((unsigned)yy >= (unsigned)H) continue;
#pragma unroll
        for (int dx = -1; dx <= 1; ++dx) {
            const int xx = px + dx;
            const int k9 = (dy + 1) * 3 + (dx + 1);
            if ((unsigned)xx < (unsigned)W) {
                const f16x8* ap = reinterpret_cast<const f16x8*>(
                    act + (((size_t)b * H + yy) * W + xx) * 64);
                const float* wp = w2 + k9;
#pragma unroll
                for (int g = 0; g < 8; ++g) {
                    const f16x8 v = ap[g];
                    const int cb = g * 8;
                    a0 = fmaf((float)v[0], wp[(cb + 0) * 9], a0);
                    a1 = fmaf((float)v[1], wp[(cb + 1) * 9], a1);
                    a2 = fmaf((float)v[2], wp[(cb + 2) * 9], a2);
                    a3 = fmaf((float)v[3], wp[(cb + 3) * 9], a3);
                    a0 = fmaf((float)v[4], wp[(cb + 4) * 9], a0);
                    a1 = fmaf((float)v[5], wp[(cb + 5) * 9], a1);
                    a2 = fmaf((float)v[6], wp[(cb + 6) * 9], a2);
                    a3 = fmaf((float)v[7], wp[(cb + 7) * 9], a3);
                }
            }
        }
    }
    psi[((size_t)b * H + py) * W + px] = ((a0 + a1) + (a2 + a3) + b2[0]) * dtp[0];
}

// K3 fast: curl + bilinear sample from NHWC fp16. Thread = 4 px x 16 ch.
__global__ __launch_bounds__(256) void k_sample_fast(
        const f16* __restrict__ Xt_r, const f16* __restrict__ Xt_i,
        const float* __restrict__ psi, float* __restrict__ out) {
    const int lane = threadIdx.x & 63;
    const int y = blockIdx.x * 4 + (threadIdx.x >> 6);
    const int b = blockIdx.y >> 3;
    const int cg = blockIdx.y & 7;
    const int px0 = lane * 4;

    const f16* src = ((cg < 4) ? Xt_r : Xt_i) + (size_t)b * HWp * 64 + (cg & 3) * 16;
    const float* pb = psi + b * HWp;

    f32x4 outv[16];
#pragma unroll
    for (int i = 0; i < 4; ++i) {
        const int px = px0 + i;
        const int yp = min(y + 1, H - 1), ym = max(y - 1, 0);
        const int xp = min(px + 1, W - 1), xm = max(px - 1, 0);
        const float u = 0.5f * (pb[yp * W + px] - pb[ym * W + px]);
        const float v = -0.5f * (pb[y * W + xp] - pb[y * W + xm]);

        const float gx = (-1.f + 2.f * px / (float)(W - 1)) - u * (2.f / (float)W);
        const float gy = (-1.f + 2.f * y / (float)(H - 1)) - v * (2.f / (float)H);

        float ix = fminf(fmaxf((gx + 1.f) * 0.5f * (float)(W - 1), 0.f), (float)(W - 1));
        float iy = fminf(fmaxf((gy + 1.f) * 0.5f * (float)(H - 1), 0.f), (float)(H - 1));
        const float xf = floorf(ix), yf = floorf(iy);
        const float wx = ix - xf, wy = iy - yf;
        const int ix0 = (int)xf, iy0 = (int)yf;
        const int ix1 = min(ix0 + 1, W - 1), iy1 = min(iy0 + 1, H - 1);

        const float w00 = (1.f - wx) * (1.f - wy), w01 = wx * (1.f - wy);
        const float w10 = (1.f - wx) * wy, w11 = wx * wy;

        const f16x8* p00 = reinterpret_cast<const f16x8*>(src + (size_t)(iy0 * W + ix0) * 64);
        const f16x8* p01 = reinterpret_cast<const f16x8*>(src + (size_t)(iy0 * W + ix1) * 64);
        const f16x8* p10 = reinterpret_cast<const f16x8*>(src + (size_t)(iy1 * W + ix0) * 64);
        const f16x8* p11 = reinterpret_cast<const f16x8*>(src + (size_t)(iy1 * W + ix1) * 64);
        const f16x8 h00a = p00[0], h00b = p00[1];
        const f16x8 h01a = p01[0], h01b = p01[1];
        const f16x8 h10a = p10[0], h10b = p10[1];
        const f16x8 h11a = p11[0], h11b = p11[1];
#pragma unroll
        for (int c = 0; c < 8; ++c)
            outv[c][i] = (float)h00a[c] * w00 + (float)h01a[c] * w01 +
                         (float)h10a[c] * w10 + (float)h11a[c] * w11;
#pragma unroll
        for (int c = 0; c < 8; ++c)
            outv[8 + c][i] = (float)h00b[c] * w00 + (float)h01b[c] * w01 +
                             (float)h10b[c] * w10 + (float)h11b[c] * w11;
    }

    float* ob = out + ((size_t)b * 128 + cg * 16) * HWp + y * W + px0;
#pragma unroll
    for (int c = 0; c < 16; ++c)
        *reinterpret_cast<f32x4*>(ob + (size_t)c * HWp) = outv[c];
}

// K3 fallback: scalar gather from fp32 NCHW.
__global__ __launch_bounds__(256) void k_sample_fb(
        const float* __restrict__ zr, const float* __restrict__ zi,
        const float* __restrict__ psi, float* __restrict__ out) {
    const int tx = threadIdx.x & 31, ty = threadIdx.x >> 5;
    const int px = blockIdx.x * 32 + tx;
    const int py = blockIdx.y * 8 + ty;
    const int b  = blockIdx.z >> 3;
    const int c0 = (blockIdx.z & 7) * 16;

    const float* pb = psi + b * HWp;
    const int yp = min(py + 1, H - 1), ym = max(py - 1, 0);
    const int xp = min(px + 1, W - 1), xm = max(px - 1, 0);
    const float u = 0.5f * (pb[yp * W + px] - pb[ym * W + px]);
    const float v = -0.5f * (pb[py * W + xp] - pb[py * W + xm]);

    const float gx = (-1.f + 2.f * px / (float)(W - 1)) - u * (2.f / (float)W);
    const float gy = (-1.f + 2.f * py / (float)(H - 1)) - v * (2.f / (float)H);

    float ix = fminf(fmaxf((gx + 1.f) * 0.5f * (float)(W - 1), 0.f), (float)(W - 1));
    float iy = fminf(fmaxf((gy + 1.f) * 0.5f * (float)(H - 1), 0.f), (float)(H - 1));
    const float xf = floorf(ix), yf = floorf(iy);
    const float wx = ix - xf, wy = iy - yf;
    const int ix0 = (int)xf, iy0 = (int)yf;
    const int ix1 = min(ix0 + 1, W - 1), iy1 = min(iy0 + 1, H - 1);

    const int o00 = iy0 * W + ix0, o01 = iy0 * W + ix1;
    const int o10 = iy1 * W + ix0, o11 = iy1 * W + ix1;
    const float w00 = (1.f - wx) * (1.f - wy), w01 = wx * (1.f - wy);
    const float w10 = (1.f - wx) * wy, w11 = wx * wy;

    const float* src0 = (c0 < 64) ? (zr + (size_t)b * 64 * HWp + (size_t)c0 * HWp)
                                  : (zi + (size_t)b * 64 * HWp + (size_t)(c0 - 64) * HWp);
    float* ob = out + ((size_t)b * 128 + c0) * HWp + py * W + px;
#pragma unroll
    for (int c = 0; c < 16; ++c) {
        const float* p = src0 + (size_t)c * HWp;
        ob[(size_t)c * HWp] = p[o00] * w00 + p[o01] * w01 + p[o10] * w10 + p[o11] * w11;
    }
}

extern "C" void kernel_launch(void* const* d_in, const int* in_sizes, int n_in,
                              void* d_out, int out_size, void* d_ws, size_t ws_size,
                              hipStream_t stream) {
    const float* z_real = (const float*)d_in[0];
    const float* z_imag = (const float*)d_in[1];
    const float* dt     = (const float*)d_in[2];
    const float* w1     = (const float*)d_in[3];
    const float* b1     = (const float*)d_in[4];
    const float* w2     = (const float*)d_in[5];
    const float* b2     = (const float*)d_in[6];

    float* out = (float*)d_out;
    char* ws = (char*)d_ws;
    f16* w1tb = (f16*)ws;                       // 73728 B

    hipLaunchKernelGGL(k_wt, dim3(144), dim3(256), 0, stream, w1, w1tb);

    if (ws_size >= NEED_FAST) {
        // ws layout: w1tb | Xt_r | Xt_i | psi  (psi last absorbs A-halo overread)
        f16* Xt_r  = (f16*)(ws + 73728);
        f16* Xt_i  = (f16*)(ws + 73728 + PLANE);
        float* psi = (float*)(ws + 73728 + 2 * PLANE);
        f16* act   = (f16*)d_out;   // consumed by conv2 before sample overwrites

        hipLaunchKernelGGL(k_xt, dim3(HWp / 64, 4), dim3(256), 0, stream, z_real, Xt_r);
        hipLaunchKernelGGL(k_xt, dim3(HWp / 64, 4), dim3(256), 0, stream, z_imag, Xt_i);
        hipLaunchKernelGGL(k_conv1, dim3(2048), dim3(256), 0, stream, Xt_r, w1tb, b1, act);
        hipLaunchKernelGGL(k_conv2, dim3(8, 32, 4), dim3(256), 0, stream, act, w2, b2, dt, psi);
        hipLaunchKernelGGL(k_sample_fast, dim3(64, 32), dim3(256), 0, stream,
                           Xt_r, Xt_i, psi, out);
    } else {
        float* psi = (float*)(ws + 73728);
        // 4KB pad before Xt so conv1's A-halo underread stays in-bounds
        f16* Xt  = (f16*)((char*)d_out + 4096);
        f16* act = (f16*)((char*)d_out + 4096 + PLANE);

        hipLaunchKernelGGL(k_xt, dim3(HWp / 64, 4), dim3(256), 0, stream, z_real, Xt);
        hipLaunchKernelGGL(k_conv1, dim3(2048), dim3(256), 0, stream, Xt, w1tb, b1, act);
        hipLaunchKernelGGL(k_conv2, dim3(8, 32, 4), dim3(256), 0, stream, act, w2, b2, dt, psi);
        hipLaunchKernelGGL(k_sample_fb, dim3(8, 32, 32), dim3(256), 0, stream,
                           z_real, z_imag, psi, out);
    }
}

// Round 8
// 165.000 us; speedup vs baseline: 1.5814x; 1.2315x over previous
//
#include <hip/hip_runtime.h>
#include <cmath>

namespace {
constexpr int H = 256, W = 256, HWp = H * W;
constexpr size_t PLANE = (size_t)4 * HWp * 64 * 2;  // one NHWC fp16 tensor, bytes
constexpr size_t NEED_FAST = 73728 + 2 * PLANE + (1u << 20);
}

typedef _Float16 f16;
typedef unsigned int u32;
typedef __attribute__((ext_vector_type(4))) _Float16 f16x4;
typedef __attribute__((ext_vector_type(8))) _Float16 f16x8;
typedef __attribute__((ext_vector_type(4))) float f32x4;
typedef __attribute__((ext_vector_type(4))) unsigned int u32x4;

__device__ __forceinline__ void dma16(const char* g, char* l) {
    __builtin_amdgcn_global_load_lds(
        (const __attribute__((address_space(1))) u32*)g,
        (__attribute__((address_space(3))) u32*)l, 16, 0, 0);
}

// K_wt: w1 [co][ci][3][3] fp32 -> w1tb [k9][co][ci] fp16
__global__ void k_wt(const float* __restrict__ w1, f16* __restrict__ w1tb) {
    int i = blockIdx.x * 256 + threadIdx.x;
    if (i >= 64 * 576) return;
    int co = i / 576, r = i - co * 576;
    int ci = r / 9, k9 = r - ci * 9;
    w1tb[(k9 * 64 + co) * 64 + ci] = (f16)w1[i];
}

// K_xt: one 64-ch plane-set NCHW fp32 -> NHWC fp16. float4 reads via LDS.
__global__ __launch_bounds__(256) void k_xt(const float* __restrict__ x,
                                            f16* __restrict__ dst) {
    __shared__ f16 tile[64][80];
    const int t = threadIdx.x;
    const int p0 = blockIdx.x * 64;
    const size_t base = (size_t)blockIdx.y * 64 * HWp;
#pragma unroll
    for (int r = 0; r < 4; ++r) {
        int q = r * 256 + t;
        int ci = q >> 4, px4 = (q & 15) * 4;
        f32x4 v = *reinterpret_cast<const f32x4*>(x + base + (size_t)ci * HWp + p0 + px4);
#pragma unroll
        for (int j = 0; j < 4; ++j) tile[px4 + j][ci] = (f16)v[j];
    }
    __syncthreads();
    const int px = t >> 2, q = t & 3;
    u32x4* d = reinterpret_cast<u32x4*>(dst + ((size_t)blockIdx.y * HWp + p0 + px) * 64 + q * 16);
    const u32x4* s = reinterpret_cast<const u32x4*>(&tile[px][q * 16]);
    d[0] = s[0];
    d[1] = s[1];
}

// K1: conv1 via MFMA, LDS-staged (global_load_lds) with XOR-swizzled layout.
__global__ __launch_bounds__(256, 2) void k_conv1(
        const f16* __restrict__ Xt,    // [B][HWp][64] fp16
        const f16* __restrict__ w1tb,  // [9][64co][64ci] fp16
        const float* __restrict__ b1,
        f16* __restrict__ act) {       // [B][HWp][64] fp16
    __shared__ __align__(16) char lds[43008];
    constexpr int WOFF = 18432;

    const int tid = threadIdx.x;
    const int lane = tid & 63, wid = tid >> 6;
    const int lr = lane & 15, lg = lane >> 4;
    const int wpx = wid & 1, wco = wid >> 1;

    const int bid = blockIdx.x;                  // 0..2047
    const int swz = (bid & 7) * 256 + (bid >> 3);
    const int b = swz >> 9;
    const int y = (swz >> 1) & 255;
    const int x0 = (swz & 1) << 7;

    const int swzb = (lane ^ ((lane >> 3) & 7)) << 4;

    f32x4 acc[4][2];
#pragma unroll
    for (int m = 0; m < 4; ++m)
#pragma unroll
        for (int n = 0; n < 2; ++n) acc[m][n] = (f32x4)0.f;

    const f16x8 zf = (f16x8)(f16)0.f;

    for (int dyi = 0; dyi < 3; ++dyi) {
        const int yy = y + dyi - 1;
        if ((unsigned)yy >= 256u) continue;

        __syncthreads();
        {
            const char* asrc = (const char*)Xt +
                ((((size_t)b * 256 + yy) * 256 + x0 - 8) * 128) + swzb;
            const char* wsrc = (const char*)w1tb + dyi * 24576 + swzb;
            for (int j = wid; j < 42; j += 4) {
                if (j < 18) dma16(asrc + j * 1024, lds + j * 1024);
                else        dma16(wsrc + (j - 18) * 1024, lds + WOFF + (j - 18) * 1024);
            }
        }
        __syncthreads();

#pragma unroll
        for (int kx = 0; kx < 3; ++kx) {
            const int dx = kx - 1;
            const int gx0 = x0 + wpx * 64 + lr + dx;
            const bool ok0 = (unsigned)gx0 < 256u;
            const bool ok3 = (unsigned)(gx0 + 48) < 256u;
            const int arow = (8 + wpx * 64 + lr + dx) << 7;
            const int axor = (lr + dx) & 7;
#pragma unroll
            for (int c = 0; c < 2; ++c) {
                const int abase = arow + (((c * 4 + lg) ^ axor) << 4);
                f16x8 A0 = *reinterpret_cast<const f16x8*>(lds + abase);
                f16x8 A1 = *reinterpret_cast<const f16x8*>(lds + abase + 2048);
                f16x8 A2 = *reinterpret_cast<const f16x8*>(lds + abase + 4096);
                f16x8 A3 = *reinterpret_cast<const f16x8*>(lds + abase + 6144);
                const int wbase = WOFF + ((kx * 64 + wco * 32 + lr) << 7)
                                + (((c * 4 + lg) ^ (lr & 7)) << 4);
                f16x8 W0 = *reinterpret_cast<const f16x8*>(lds + wbase);
                f16x8 W1 = *reinterpret_cast<const f16x8*>(lds + wbase + 2048);
                A0 = ok0 ? A0 : zf;
                A3 = ok3 ? A3 : zf;
                acc[0][0] = __builtin_amdgcn_mfma_f32_16x16x32_f16(W0, A0, acc[0][0], 0, 0, 0);
                acc[0][1] = __builtin_amdgcn_mfma_f32_16x16x32_f16(W1, A0, acc[0][1], 0, 0, 0);
                acc[1][0] = __builtin_amdgcn_mfma_f32_16x16x32_f16(W0, A1, acc[1][0], 0, 0, 0);
                acc[1][1] = __builtin_amdgcn_mfma_f32_16x16x32_f16(W1, A1, acc[1][1], 0, 0, 0);
                acc[2][0] = __builtin_amdgcn_mfma_f32_16x16x32_f16(W0, A2, acc[2][0], 0, 0, 0);
                acc[2][1] = __builtin_amdgcn_mfma_f32_16x16x32_f16(W1, A2, acc[2][1], 0, 0, 0);
                acc[3][0] = __builtin_amdgcn_mfma_f32_16x16x32_f16(W0, A3, acc[3][0], 0, 0, 0);
                acc[3][1] = __builtin_amdgcn_mfma_f32_16x16x32_f16(W1, A3, acc[3][1], 0, 0, 0);
            }
        }
    }

    float bias[2][4];
#pragma unroll
    for (int n = 0; n < 2; ++n) {
        f32x4 bv = *reinterpret_cast<const f32x4*>(b1 + wco * 32 + n * 16 + lg * 4);
#pragma unroll
        for (int r = 0; r < 4; ++r) bias[n][r] = bv[r];
    }
    const size_t row_base = ((size_t)b * 256 + y) * 256;
#pragma unroll
    for (int m = 0; m < 4; ++m) {
        f16* ap = act + (row_base + x0 + wpx * 64 + m * 16 + lr) * 64 + wco * 32 + lg * 4;
#pragma unroll
        for (int n = 0; n < 2; ++n) {
            f16x4 o;
#pragma unroll
            for (int r = 0; r < 4; ++r) {
                float v = acc[m][n][r] + bias[n][r];
                v = v / (1.f + __expf(-v));
                o[r] = (f16)v;
            }
            *reinterpret_cast<f16x4*>(ap + n * 16) = o;
        }
    }
}

// K2: conv2 (64->1) + *dt -> psi. NHWC fp16 input, f16x8 vector loads.
__global__ __launch_bounds__(256) void k_conv2(
        const f16* __restrict__ act, const float* __restrict__ w2,
        const float* __restrict__ b2, const float* __restrict__ dtp,
        float* __restrict__ psi) {
    const int tx = threadIdx.x & 31, ty = threadIdx.x >> 5;
    const int px = blockIdx.x * 32 + tx;
    const int py = blockIdx.y * 8 + ty;
    const int b = blockIdx.z;

    float a0 = 0.f, a1 = 0.f, a2 = 0.f, a3 = 0.f;
#pragma unroll
    for (int dy = -1; dy <= 1; ++dy) {
        const int yy = py + dy;
        if ((unsigned)yy >= (unsigned)H) continue;
#pragma unroll
        for (int dx = -1; dx <= 1; ++dx) {
            const int xx = px + dx;
            const int k9 = (dy + 1) * 3 + (dx + 1);
            if ((unsigned)xx < (unsigned)W) {
                const f16x8* ap = reinterpret_cast<const f16x8*>(
                    act + (((size_t)b * H + yy) * W + xx) * 64);
                const float* wp = w2 + k9;
#pragma unroll
                for (int g = 0; g < 8; ++g) {
                    const f16x8 v = ap[g];
                    const int cb = g * 8;
                    a0 = fmaf((float)v[0], wp[(cb + 0) * 9], a0);
                    a1 = fmaf((float)v[1], wp[(cb + 1) * 9], a1);
                    a2 = fmaf((float)v[2], wp[(cb + 2) * 9], a2);
                    a3 = fmaf((float)v[3], wp[(cb + 3) * 9], a3);
                    a0 = fmaf((float)v[4], wp[(cb + 4) * 9], a0);
                    a1 = fmaf((float)v[5], wp[(cb + 5) * 9], a1);
                    a2 = fmaf((float)v[6], wp[(cb + 6) * 9], a2);
                    a3 = fmaf((float)v[7], wp[(cb + 7) * 9], a3);
                }
            }
        }
    }
    psi[((size_t)b * H + py) * W + px] = ((a0 + a1) + (a2 + a3) + b2[0]) * dtp[0];
}

// K3 v3: block = 1 row-half (128 px) x ALL 128 channels.
// Phase A: flow/corners once per px -> LDS SoA.
// Phase B per plane: 2 lanes/px read full 128B records (coalesced 16B loads),
// interpolate 32 ch/lane, transpose via padded LDS, store 512B-contig chunks.
__global__ __launch_bounds__(256, 4) void k_sample3(
        const f16* __restrict__ Xt_r, const f16* __restrict__ Xt_i,
        const float* __restrict__ psi, float* __restrict__ out) {
    __shared__ int   s_off[4][128];
    __shared__ float s_w[4][128];
    __shared__ __align__(16) float s_stage[64][132];

    const int tid = threadIdx.x;
    const int bid = blockIdx.x;                  // 0..2047
    const int swz = (bid & 7) * 256 + (bid >> 3);
    const int seg = swz & 1, y = (swz >> 1) & 255, b = swz >> 9;
    const int x0 = seg * 128;

    if (tid < 128) {
        const int px = x0 + tid;
        const float* pb = psi + b * HWp;
        const int yp = min(y + 1, H - 1), ym = max(y - 1, 0);
        const int xp = min(px + 1, W - 1), xm = max(px - 1, 0);
        const float u = 0.5f * (pb[yp * W + px] - pb[ym * W + px]);
        const float v = -0.5f * (pb[y * W + xp] - pb[y * W + xm]);
        const float gx = (-1.f + 2.f * px / (float)(W - 1)) - u * (2.f / (float)W);
        const float gy = (-1.f + 2.f * y / (float)(H - 1)) - v * (2.f / (float)H);
        float ix = fminf(fmaxf((gx + 1.f) * 0.5f * (float)(W - 1), 0.f), (float)(W - 1));
        float iy = fminf(fmaxf((gy + 1.f) * 0.5f * (float)(H - 1), 0.f), (float)(H - 1));
        const float xf = floorf(ix), yf = floorf(iy);
        const float wx = ix - xf, wy = iy - yf;
        const int ix0 = (int)xf, iy0 = (int)yf;
        const int ix1 = min(ix0 + 1, W - 1), iy1 = min(iy0 + 1, H - 1);
        s_off[0][tid] = (iy0 * W + ix0) * 128;
        s_off[1][tid] = (iy0 * W + ix1) * 128;
        s_off[2][tid] = (iy1 * W + ix0) * 128;
        s_off[3][tid] = (iy1 * W + ix1) * 128;
        s_w[0][tid] = (1.f - wx) * (1.f - wy);
        s_w[1][tid] = wx * (1.f - wy);
        s_w[2][tid] = (1.f - wx) * wy;
        s_w[3][tid] = wx * wy;
    }
    __syncthreads();

    const int p = tid >> 1, s = tid & 1;
    const int o0 = s_off[0][p], o1 = s_off[1][p], o2 = s_off[2][p], o3 = s_off[3][p];
    const float w0 = s_w[0][p], w1 = s_w[1][p], w2 = s_w[2][p], w3 = s_w[3][p];
    const int cl = tid >> 5;                 // 0..7
    const int pxq = (tid & 31) * 4;          // px chunk for store phase
    const size_t obase = (size_t)b * 128 * HWp + (size_t)y * W + x0 + pxq;

#pragma unroll
    for (int pl = 0; pl < 2; ++pl) {
        const char* base = (const char*)(pl ? Xt_i : Xt_r)
                         + (size_t)b * HWp * 128 + s * 64;
        const char* c0 = base + o0;
        const char* c1 = base + o1;
        const char* c2 = base + o2;
        const char* c3 = base + o3;
        f16x8 h00 = *(const f16x8*)(c0);      f16x8 h01 = *(const f16x8*)(c0 + 16);
        f16x8 h02 = *(const f16x8*)(c0 + 32); f16x8 h03 = *(const f16x8*)(c0 + 48);
        f16x8 h10 = *(const f16x8*)(c1);      f16x8 h11 = *(const f16x8*)(c1 + 16);
        f16x8 h12 = *(const f16x8*)(c1 + 32); f16x8 h13 = *(const f16x8*)(c1 + 48);
        f16x8 h20 = *(const f16x8*)(c2);      f16x8 h21 = *(const f16x8*)(c2 + 16);
        f16x8 h22 = *(const f16x8*)(c2 + 32); f16x8 h23 = *(const f16x8*)(c2 + 48);
        f16x8 h30 = *(const f16x8*)(c3);      f16x8 h31 = *(const f16x8*)(c3 + 16);
        f16x8 h32 = *(const f16x8*)(c3 + 32); f16x8 h33 = *(const f16x8*)(c3 + 48);

        const int rb = s << 5;
#pragma unroll
        for (int k = 0; k < 8; ++k) {
            s_stage[rb + k][p] = w0 * (float)h00[k] + w1 * (float)h10[k]
                               + w2 * (float)h20[k] + w3 * (float)h30[k];
            s_stage[rb + 8 + k][p] = w0 * (float)h01[k] + w1 * (float)h11[k]
                                   + w2 * (float)h21[k] + w3 * (float)h31[k];
            s_stage[rb + 16 + k][p] = w0 * (float)h02[k] + w1 * (float)h12[k]
                                    + w2 * (float)h22[k] + w3 * (float)h32[k];
            s_stage[rb + 24 + k][p] = w0 * (float)h03[k] + w1 * (float)h13[k]
                                    + w2 * (float)h23[k] + w3 * (float)h33[k];
        }
        __syncthreads();
#pragma unroll
        for (int k = 0; k < 8; ++k) {
            const int c = cl + (k << 3);
            f32x4 vv = *(const f32x4*)&s_stage[c][pxq];
            *(f32x4*)(out + obase + (size_t)(pl * 64 + c) * HWp) = vv;
        }
        __syncthreads();
    }
}

// K3 fallback: scalar gather from fp32 NCHW.
__global__ __launch_bounds__(256) void k_sample_fb(
        const float* __restrict__ zr, const float* __restrict__ zi,
        const float* __restrict__ psi, float* __restrict__ out) {
    const int tx = threadIdx.x & 31, ty = threadIdx.x >> 5;
    const int px = blockIdx.x * 32 + tx;
    const int py = blockIdx.y * 8 + ty;
    const int b  = blockIdx.z >> 3;
    const int c0 = (blockIdx.z & 7) * 16;

    const float* pb = psi + b * HWp;
    const int yp = min(py + 1, H - 1), ym = max(py - 1, 0);
    const int xp = min(px + 1, W - 1), xm = max(px - 1, 0);
    const float u = 0.5f * (pb[yp * W + px] - pb[ym * W + px]);
    const float v = -0.5f * (pb[py * W + xp] - pb[py * W + xm]);

    const float gx = (-1.f + 2.f * px / (float)(W - 1)) - u * (2.f / (float)W);
    const float gy = (-1.f + 2.f * py / (float)(H - 1)) - v * (2.f / (float)H);

    float ix = fminf(fmaxf((gx + 1.f) * 0.5f * (float)(W - 1), 0.f), (float)(W - 1));
    float iy = fminf(fmaxf((gy + 1.f) * 0.5f * (float)(H - 1), 0.f), (float)(H - 1));
    const float xf = floorf(ix), yf = floorf(iy);
    const float wx = ix - xf, wy = iy - yf;
    const int ix0 = (int)xf, iy0 = (int)yf;
    const int ix1 = min(ix0 + 1, W - 1), iy1 = min(iy0 + 1, H - 1);

    const int o00 = iy0 * W + ix0, o01 = iy0 * W + ix1;
    const int o10 = iy1 * W + ix0, o11 = iy1 * W + ix1;
    const float w00 = (1.f - wx) * (1.f - wy), w01 = wx * (1.f - wy);
    const float w10 = (1.f - wx) * wy, w11 = wx * wy;

    const float* src0 = (c0 < 64) ? (zr + (size_t)b * 64 * HWp + (size_t)c0 * HWp)
                                  : (zi + (size_t)b * 64 * HWp + (size_t)(c0 - 64) * HWp);
    float* ob = out + ((size_t)b * 128 + c0) * HWp + py * W + px;
#pragma unroll
    for (int c = 0; c < 16; ++c) {
        const float* p = src0 + (size_t)c * HWp;
        ob[(size_t)c * HWp] = p[o00] * w00 + p[o01] * w01 + p[o10] * w10 + p[o11] * w11;
    }
}

extern "C" void kernel_launch(void* const* d_in, const int* in_sizes, int n_in,
                              void* d_out, int out_size, void* d_ws, size_t ws_size,
                              hipStream_t stream) {
    const float* z_real = (const float*)d_in[0];
    const float* z_imag = (const float*)d_in[1];
    const float* dt     = (const float*)d_in[2];
    const float* w1     = (const float*)d_in[3];
    const float* b1     = (const float*)d_in[4];
    const float* w2     = (const float*)d_in[5];
    const float* b2     = (const float*)d_in[6];

    float* out = (float*)d_out;
    char* ws = (char*)d_ws;
    f16* w1tb = (f16*)ws;                       // 73728 B

    hipLaunchKernelGGL(k_wt, dim3(144), dim3(256), 0, stream, w1, w1tb);

    if (ws_size >= NEED_FAST) {
        // ws layout: w1tb | Xt_r | Xt_i | psi
        f16* Xt_r  = (f16*)(ws + 73728);
        f16* Xt_i  = (f16*)(ws + 73728 + PLANE);
        float* psi = (float*)(ws + 73728 + 2 * PLANE);
        f16* act   = (f16*)d_out;   // consumed by conv2 before sample overwrites

        hipLaunchKernelGGL(k_xt, dim3(HWp / 64, 4), dim3(256), 0, stream, z_real, Xt_r);
        hipLaunchKernelGGL(k_xt, dim3(HWp / 64, 4), dim3(256), 0, stream, z_imag, Xt_i);
        hipLaunchKernelGGL(k_conv1, dim3(2048), dim3(256), 0, stream, Xt_r, w1tb, b1, act);
        hipLaunchKernelGGL(k_conv2, dim3(8, 32, 4), dim3(256), 0, stream, act, w2, b2, dt, psi);
        hipLaunchKernelGGL(k_sample3, dim3(2048), dim3(256), 0, stream,
                           Xt_r, Xt_i, psi, out);
    } else {
        float* psi = (float*)(ws + 73728);
        f16* Xt  = (f16*)((char*)d_out + 4096);
        f16* act = (f16*)((char*)d_out + 4096 + PLANE);

        hipLaunchKernelGGL(k_xt, dim3(HWp / 64, 4), dim3(256), 0, stream, z_real, Xt);
        hipLaunchKernelGGL(k_conv1, dim3(2048), dim3(256), 0, stream, Xt, w1tb, b1, act);
        hipLaunchKernelGGL(k_conv2, dim3(8, 32, 4), dim3(256), 0, stream, act, w2, b2, dt, psi);
        hipLaunchKernelGGL(k_sample_fb, dim3(8, 32, 32), dim3(256), 0, stream,
                           z_real, z_imag, psi, out);
    }
}